// Round 2
// baseline (517.760 us; speedup 1.0000x reference)
//
#include <hip/hip_runtime.h>

#define C_   128
#define P_   4096
#define K3   384
#define CP   (C_*P_)
#define NB_  32

typedef __attribute__((ext_vector_type(8))) short short8;
typedef __attribute__((ext_vector_type(4))) short short4v;
typedef __attribute__((ext_vector_type(4))) float f32x4;

__device__ __forceinline__ short f2bf(float f) {
  union { float f; unsigned u; } v; v.f = f;
  unsigned r = v.u + 0x7fffu + ((v.u >> 16) & 1u);
  return (short)(r >> 16);
}
__device__ __forceinline__ float bf2f(short b) {
  union { unsigned u; float f; } v; v.u = ((unsigned)(unsigned short)b) << 16;
  return v.f;
}
__device__ __forceinline__ void gl_lds16(const void* g, void* l) {
  __builtin_amdgcn_global_load_lds(
      (const __attribute__((address_space(1))) unsigned int*)g,
      (__attribute__((address_space(3))) unsigned int*)l, 16, 0, 0);
}

// ---- prep: permuted bf16 weights  w3p[m][j*128+c] = w3[m][c*3+j], same for w6 ----
__global__ __launch_bounds__(256) void prep_kernel(const float* __restrict__ w3,
                                                   const float* __restrict__ w6,
                                                   short* __restrict__ w3p,
                                                   short* __restrict__ w6p) {
  int idx = blockIdx.x * 256 + threadIdx.x;      // 49152 = 128*384
  int m = idx / K3, kp = idx - m * K3;
  int j = kp >> 7, c = kp & 127;
  w3p[idx] = f2bf(w3[m * K3 + c * 3 + j]);
  w6p[idx] = f2bf(w6[m * K3 + c * 3 + j]);
}

// ---- t5k: xb (bf16 natural), xT (bf16 [p][c]), t5T (bf16 [p][c]) ----
__global__ __launch_bounds__(256) void t5k_kernel(const float* __restrict__ x,
                                                  const float* __restrict__ p5,
                                                  short* __restrict__ xb,
                                                  short* __restrict__ xT,
                                                  short* __restrict__ t5T) {
  int b = blockIdx.x;                 // 32n * 2ct * 64pt = 4096
  int pt = b & 63, ct = (b >> 6) & 1, n = b >> 7;
  int p0 = pt * 64, c0 = ct * 64;
  const float* xn = x + (size_t)n * CP;
  short* xbn = xb + (size_t)n * CP;
  short* xTn = xT + (size_t)n * CP;
  short* tTn = t5T + (size_t)n * CP;
  __shared__ short Ls[64][68];
  __shared__ short Ms[64][68];
  int tid = threadIdx.x;
  short xr[16];
#pragma unroll
  for (int it = 0; it < 4; ++it) {
    int fid = tid + it * 256;
    int i = fid >> 4, j4 = fid & 15;
    f32x4 v = *(const f32x4*)(xn + (c0 + i) * P_ + p0 + j4 * 4);
    short4v s;
#pragma unroll
    for (int r = 0; r < 4; ++r) { s[r] = f2bf(v[r]); xr[it * 4 + r] = s[r]; }
    *(short4v*)(xbn + (c0 + i) * P_ + p0 + j4 * 4) = s;
    *(short4v*)(&Ls[i][j4 * 4]) = s;
  }
  __syncthreads();
#pragma unroll
  for (int it = 0; it < 4; ++it) {
    int fid = tid + it * 256;
    int i = fid >> 4, j4 = fid & 15, jb = j4 * 4;
    float c0v = bf2f(xr[it * 4 + 0]), c1v = bf2f(xr[it * 4 + 1]);
    float c2v = bf2f(xr[it * 4 + 2]), c3v = bf2f(xr[it * 4 + 3]);
    float L0 = (jb > 0) ? bf2f(Ls[i][jb - 2]) : 0.f;
    float L1 = (jb > 0) ? bf2f(Ls[i][jb - 1]) : 0.f;
    float R2 = (jb < 60) ? bf2f(Ls[i][jb + 4]) : 0.f;
    float R3 = (jb < 60) ? bf2f(Ls[i][jb + 5]) : 0.f;
    f32x4 pv = *(const f32x4*)(p5 + p0 + jb);
    short4v s;
    s[0] = f2bf(pv[0] * fmaxf(fmaxf(L0, c0v), c2v));
    s[1] = f2bf(pv[1] * fmaxf(fmaxf(L1, c1v), c3v));
    s[2] = f2bf(pv[2] * fmaxf(fmaxf(c0v, c2v), R2));
    s[3] = f2bf(pv[3] * fmaxf(fmaxf(c1v, c3v), R3));
    *(short4v*)(&Ms[i][jb]) = s;
  }
  __syncthreads();
#pragma unroll
  for (int it = 0; it < 4; ++it) {
    int oid = tid + it * 256;
    int pr = oid >> 4, cg = oid & 15, cb = cg * 4;
    short4v a, bq;
#pragma unroll
    for (int r = 0; r < 4; ++r) { a[r] = Ls[cb + r][pr]; bq[r] = Ms[cb + r][pr]; }
    *(short4v*)(xTn + (p0 + pr) * C_ + c0 + cb) = a;
    *(short4v*)(tTn + (p0 + pr) * C_ + c0 + cb) = bq;
  }
}

// ---- g12: fused g1 (t3T = w3 @ t1) and g2 (t6/t7 from w6 @ t5shift) ----
__global__ __launch_bounds__(256) void g12_kernel(const float* __restrict__ x,
                                                  const short* __restrict__ w3p,
                                                  const short* __restrict__ w6p,
                                                  const short* __restrict__ xT,
                                                  const short* __restrict__ t5T,
                                                  short* __restrict__ t3T,
                                                  short* __restrict__ t6T,
                                                  short* __restrict__ t7,
                                                  short* __restrict__ t7T) {
  int blk = blockIdx.x;
  int role = blk & 1;                 // 1: g1 (t3), 0: g2 (t6/t7)
  int b = blk >> 1;
  int n = b >> 5, pt = b & 31, p0 = pt * 128;
  int tid = threadIdx.x, lane = tid & 63, wv = tid >> 6;
  int wm = (wv & 1) * 64, wp = (wv >> 1) * 64;
  const short* Ap = role ? w3p : w6p;
  const short* BTn = (role ? xT : t5T) + (size_t)n * CP;
  __shared__ __align__(16) short As[4][128][8];
  __shared__ __align__(16) short Bs[4][128][8];
  f32x4 acc[4][4] = {};
  for (int ks = 0; ks < 12; ++ks) {
    int k0 = ks * 32;
    int jr = ks >> 2;
    __syncthreads();
#pragma unroll
    for (int it = 0; it < 2; ++it) {
      int slot = tid + it * 256;
      int q = slot >> 7, m = slot & 127;
      gl_lds16(Ap + m * K3 + k0 + q * 8, &As[q][m][0]);
    }
#pragma unroll
    for (int it = 0; it < 2; ++it) {
      int slot = tid + it * 256;
      int q = slot >> 7, pc = slot & 127;
      int p = p0 + pc;
      int c0k = ((ks & 3) * 32) + q * 8;
      int prow; bool valid;
      if (role) {
        int d = 2 * (jr - 1);
        int wd = (p & 63) + d;
        valid = (wd >= 0 && wd < 64);
        prow = p + d;
      } else {
        prow = p + 192 * (jr - 1);
        valid = (prow >= 0 && prow < P_);
      }
      int pcl = min(max(prow, 0), P_ - 1);
      short8 v = *(const short8*)(BTn + pcl * C_ + c0k);
      short8 zero = {};
      if (!valid) v = zero;
      *(short8*)(&Bs[q][pc][0]) = v;
    }
    __syncthreads();
    int row = lane & 15, q = lane >> 4;
    short8 a[4], bb[4];
#pragma unroll
    for (int im = 0; im < 4; ++im) a[im] = *(const short8*)(&As[q][wm + im * 16 + row][0]);
#pragma unroll
    for (int ip = 0; ip < 4; ++ip) bb[ip] = *(const short8*)(&Bs[q][wp + ip * 16 + row][0]);
#pragma unroll
    for (int im = 0; im < 4; ++im)
#pragma unroll
      for (int ip = 0; ip < 4; ++ip)
        acc[im][ip] = __builtin_amdgcn_mfma_f32_16x16x32_bf16(a[im], bb[ip], acc[im][ip], 0, 0, 0);
  }
  int col = lane & 15, rq = lane >> 4;
  if (role) {
    short* t3Tn = t3T + (size_t)n * CP;
#pragma unroll
    for (int im = 0; im < 4; ++im)
#pragma unroll
      for (int ip = 0; ip < 4; ++ip) {
        int m0 = wm + im * 16 + rq * 4;
        int p = p0 + wp + ip * 16 + col;
        short4v s;
#pragma unroll
        for (int r = 0; r < 4; ++r) s[r] = f2bf(acc[im][ip][r]);
        *(short4v*)(t3Tn + p * C_ + m0) = s;
      }
  } else {
    const float* xn = x + (size_t)n * CP;
    short* t6Tn = t6T + (size_t)n * CP;
    short* t7n  = t7  + (size_t)n * CP;
    short* t7Tn = t7T + (size_t)n * CP;
#pragma unroll
    for (int im = 0; im < 4; ++im)
#pragma unroll
      for (int ip = 0; ip < 4; ++ip) {
        int m0 = wm + im * 16 + rq * 4;
        int p = p0 + wp + ip * 16 + col;
        short4v s6, s7;
#pragma unroll
        for (int r = 0; r < 4; ++r) {
          float t6v = acc[im][ip][r];
          float xv = xn[(m0 + r) * P_ + p];
          float t7v = fmaxf(xv, t6v);
          s6[r] = f2bf(t6v);
          s7[r] = f2bf(t7v);
          t7n[(m0 + r) * P_ + p] = s7[r];
        }
        *(short4v*)(t6Tn + p * C_ + m0) = s6;
        *(short4v*)(t7Tn + p * C_ + m0) = s7;
      }
  }
}

// ---- g3: t9raw[c][k'=j*128+cB] += sum_p t7[c,p] * t1[(cB,j),p]  (split-K=8) ----
__global__ __launch_bounds__(256) void g3_kernel(const short* __restrict__ xb,
                                                 const short* __restrict__ t7,
                                                 float* __restrict__ t9) {
  int blk = blockIdx.x;                 // 768 = 3 * 32 * 8
  int nb = blk % 3;
  int tmp = blk / 3;
  int n = tmp & 31, sk = tmp >> 5;
  int d = 2 * (nb - 1);
  int tid = threadIdx.x, lane = tid & 63, wv = tid >> 6;
  int wm = (wv & 1) * 64, wp = (wv >> 1) * 64;
  const short* xbn = xb + (size_t)n * CP;
  const short* t7n = t7 + (size_t)n * CP;
  __shared__ __align__(16) short As[4][128][8];
  __shared__ __align__(16) short Bs[4][128][8];
  f32x4 acc[4][4] = {};
  for (int ks = 0; ks < 16; ++ks) {
    int pp0 = sk * 512 + ks * 32;
    __syncthreads();
#pragma unroll
    for (int it = 0; it < 2; ++it) {
      int slot = tid + it * 256;
      int q = slot >> 7, c = slot & 127;
      gl_lds16(t7n + c * P_ + pp0 + q * 8, &As[q][c][0]);
    }
#pragma unroll
    for (int it = 0; it < 2; ++it) {
      int slot = tid + it * 256;
      int q = slot >> 7, kc = slot & 127;
      int pb = pp0 + q * 8;
      const int* src = (const int*)(xbn + kc * P_ + pb + d);   // 4B-aligned
      union { int i[4]; short8 s; } u;
#pragma unroll
      for (int t = 0; t < 4; ++t) u.i[t] = src[t];
      short8 v = u.s;
      int w0 = pb & 63;
      if (nb == 0) { if (w0 == 0) { v[0] = 0; v[1] = 0; } }
      else if (nb == 2) { if (w0 == 56) { v[6] = 0; v[7] = 0; } }
      *(short8*)(&Bs[q][kc][0]) = v;
    }
    __syncthreads();
    int row = lane & 15, q = lane >> 4;
    short8 a[4], bb[4];
#pragma unroll
    for (int im = 0; im < 4; ++im) a[im] = *(const short8*)(&As[q][wm + im * 16 + row][0]);
#pragma unroll
    for (int ip = 0; ip < 4; ++ip) bb[ip] = *(const short8*)(&Bs[q][wp + ip * 16 + row][0]);
#pragma unroll
    for (int im = 0; im < 4; ++im)
#pragma unroll
      for (int ip = 0; ip < 4; ++ip)
        acc[im][ip] = __builtin_amdgcn_mfma_f32_16x16x32_bf16(a[im], bb[ip], acc[im][ip], 0, 0, 0);
  }
  int col = lane & 15, rq = lane >> 4;
  float* t9n = t9 + (size_t)n * (C_ * K3);
#pragma unroll
  for (int im = 0; im < 4; ++im)
#pragma unroll
    for (int ip = 0; ip < 4; ++ip)
#pragma unroll
      for (int r = 0; r < 4; ++r) {
        int c = wm + im * 16 + rq * 4 + r;
        int kp = nb * 128 + wp + ip * 16 + col;
        atomicAdd(&t9n[c * K3 + kp], acc[im][ip][r]);
      }
}

// ---- g4: out[c][p] = sum_k' A[c][k'] * t12[k'][p];  A = t9raw * p8[c] * scale ----
__global__ __launch_bounds__(256) void g4_kernel(const float* __restrict__ t9,
                                                 const float* __restrict__ p8,
                                                 const float* __restrict__ p12,
                                                 const short* __restrict__ t3T,
                                                 const short* __restrict__ t6T,
                                                 const short* __restrict__ t7T,
                                                 const short* __restrict__ xT,
                                                 float* __restrict__ out) {
  int b = blockIdx.x;                    // 1024
  int n = b >> 5, pt = b & 31, p0 = pt * 128;
  int tid = threadIdx.x, lane = tid & 63, wv = tid >> 6;
  int wm = (wv & 1) * 64, wp = (wv >> 1) * 64;
  const float* t9n = t9 + (size_t)n * (C_ * K3);
  const short* t3n = t3T + (size_t)n * CP;
  const short* t6n = t6T + (size_t)n * CP;
  const short* t7n = t7T + (size_t)n * CP;
  const short* xTn = xT + (size_t)n * CP;
  const float INV = 1.0f / (64.0f * 19.5959179423f);    // 1/(64*sqrt(384))
  __shared__ __align__(16) short As[4][128][8];
  __shared__ __align__(16) short Bs[4][128][8];
  f32x4 acc[4][4] = {};
  for (int ks = 0; ks < 12; ++ks) {
    int k0 = ks * 32;
    int j = ks >> 2, d = 2 * (j - 1);
    __syncthreads();
#pragma unroll
    for (int it = 0; it < 2; ++it) {
      int slot = tid + it * 256;
      int q = slot >> 7, m = slot & 127;
      const float* ar = t9n + m * K3 + k0 + q * 8;
      f32x4 u0 = *(const f32x4*)ar;
      f32x4 u1 = *(const f32x4*)(ar + 4);
      float sc = p8[m] * INV;
      short8 v;
#pragma unroll
      for (int r = 0; r < 4; ++r) { v[r] = f2bf(u0[r] * sc); v[r + 4] = f2bf(u1[r] * sc); }
      *(short8*)(&As[q][m][0]) = v;
    }
#pragma unroll
    for (int it = 0; it < 2; ++it) {
      int slot = tid + it * 256;
      int q = slot >> 7, pc = slot & 127;
      int p = p0 + pc;
      int c0k = ((ks & 3) * 32) + q * 8;
      float s12 = p12[j * 64 + (p >> 6)];
      size_t base = (size_t)p * C_ + c0k;
      short8 a6 = *(const short8*)(t6n + base);
      short8 a7 = *(const short8*)(t7n + base);
      short8 a3 = *(const short8*)(t3n + base);
      int wd = (p & 63) + d;
      bool valid = (wd >= 0 && wd < 64);
      int pr = min(max(p + d, 0), P_ - 1);
      short8 ax = *(const short8*)(xTn + pr * C_ + c0k);
      short8 zero = {};
      if (!valid) ax = zero;
      short8 v;
#pragma unroll
      for (int jj = 0; jj < 8; ++jj) {
        float t11 = fmaxf(bf2f(a6[jj]), bf2f(a7[jj]) + fmaxf(bf2f(a3[jj]), bf2f(ax[jj])));
        v[jj] = f2bf(s12 * t11);
      }
      *(short8*)(&Bs[q][pc][0]) = v;
    }
    __syncthreads();
    int row = lane & 15, q = lane >> 4;
    short8 a[4], bb[4];
#pragma unroll
    for (int im = 0; im < 4; ++im) a[im] = *(const short8*)(&As[q][wm + im * 16 + row][0]);
#pragma unroll
    for (int ip = 0; ip < 4; ++ip) bb[ip] = *(const short8*)(&Bs[q][wp + ip * 16 + row][0]);
#pragma unroll
    for (int im = 0; im < 4; ++im)
#pragma unroll
      for (int ip = 0; ip < 4; ++ip)
        acc[im][ip] = __builtin_amdgcn_mfma_f32_16x16x32_bf16(a[im], bb[ip], acc[im][ip], 0, 0, 0);
  }
  int col = lane & 15, rq = lane >> 4;
#pragma unroll
  for (int im = 0; im < 4; ++im)
#pragma unroll
    for (int ip = 0; ip < 4; ++ip)
#pragma unroll
      for (int r = 0; r < 4; ++r) {
        int m = wm + im * 16 + rq * 4 + r;
        int p = p0 + wp + ip * 16 + col;
        out[(size_t)n * CP + m * P_ + p] = acc[im][ip][r];
      }
}

extern "C" void kernel_launch(void* const* d_in, const int* in_sizes, int n_in,
                              void* d_out, int out_size, void* d_ws, size_t ws_size,
                              hipStream_t stream) {
  const float* x   = (const float*)d_in[0];
  const float* w3  = (const float*)d_in[1];
  const float* p5  = (const float*)d_in[2];
  const float* w6  = (const float*)d_in[3];
  const float* p8  = (const float*)d_in[4];
  const float* p12 = (const float*)d_in[5];
  float* out = (float*)d_out;

  char* ws = (char*)d_ws;
  const size_t RB = (size_t)NB_ * CP * 2;       // 32 MiB per bf16 tensor
  size_t off = 256;                              // guard before xb (pb-2 underflow reads)
  short* xb  = (short*)(ws + off); off += RB;
  short* xT  = (short*)(ws + off); off += RB;
  short* t5T = (short*)(ws + off); off += RB;    // reused as t9 after g12
  short* t3T = (short*)(ws + off); off += RB;
  short* t6T = (short*)(ws + off); off += RB;
  short* t7  = (short*)(ws + off); off += RB;
  short* t7T = (short*)(ws + off); off += RB;
  short* w3p = (short*)(ws + off); off += 49152 * 2;
  short* w6p = (short*)(ws + off); off += 49152 * 2;
  float* t9  = (float*)t5T;                      // 6.3 MiB, live only after g12

  prep_kernel<<<192, 256, 0, stream>>>(w3, w6, w3p, w6p);
  t5k_kernel<<<4096, 256, 0, stream>>>(x, p5, xb, xT, t5T);
  g12_kernel<<<2048, 256, 0, stream>>>(x, w3p, w6p, xT, t5T, t3T, t6T, t7, t7T);
  hipMemsetAsync(t9, 0, (size_t)NB_ * C_ * K3 * sizeof(float), stream);
  g3_kernel<<<768, 256, 0, stream>>>(xb, t7, t9);
  g4_kernel<<<1024, 256, 0, stream>>>(t9, p8, p12, t3T, t6T, t7T, xT, out);
}

// Round 3
// 446.883 us; speedup vs baseline: 1.1586x; 1.1586x over previous
//
#include <hip/hip_runtime.h>

#define C_   128
#define P_   4096
#define K3   384
#define CP   (C_*P_)
#define NB_  32

typedef __attribute__((ext_vector_type(8))) short short8;
typedef __attribute__((ext_vector_type(4))) short short4v;
typedef __attribute__((ext_vector_type(4))) float f32x4;

__device__ __forceinline__ short f2bf(float f) {
  union { float f; unsigned u; } v; v.f = f;
  unsigned r = v.u + 0x7fffu + ((v.u >> 16) & 1u);
  return (short)(r >> 16);
}
__device__ __forceinline__ float bf2f(short b) {
  union { unsigned u; float f; } v; v.u = ((unsigned)(unsigned short)b) << 16;
  return v.f;
}
__device__ __forceinline__ void gl_lds16(const void* g, void* l) {
  __builtin_amdgcn_global_load_lds(
      (const __attribute__((address_space(1))) unsigned int*)g,
      (__attribute__((address_space(3))) unsigned int*)l, 16, 0, 0);
}

// ---- prep: permuted bf16 weights  wXp[m][j*128+c] = wX[m][c*3+j] ----
__global__ __launch_bounds__(256) void prep_kernel(const float* __restrict__ w3,
                                                   const float* __restrict__ w6,
                                                   short* __restrict__ w3p,
                                                   short* __restrict__ w6p) {
  int idx = blockIdx.x * 256 + threadIdx.x;      // 49152 = 128*384
  int m = idx / K3, kp = idx - m * K3;
  int j = kp >> 7, c = kp & 127;
  w3p[idx] = f2bf(w3[m * K3 + c * 3 + j]);
  w6p[idx] = f2bf(w6[m * K3 + c * 3 + j]);
}

// ---- xk: x fp32 -> xb (bf16 natural [c][p]) + xT (bf16 [p][c]) ----
__global__ __launch_bounds__(256) void xk_kernel(const float* __restrict__ x,
                                                 short* __restrict__ xb,
                                                 short* __restrict__ xT) {
  int b = blockIdx.x;                 // 32n * 2ct * 64pt = 4096
  int pt = b & 63, ct = (b >> 6) & 1, n = b >> 7;
  int p0 = pt * 64, c0 = ct * 64;
  const float* xn = x + (size_t)n * CP;
  short* xbn = xb + (size_t)n * CP;
  short* xTn = xT + (size_t)n * CP;
  __shared__ short Ls[64][68];
  int tid = threadIdx.x;
#pragma unroll
  for (int it = 0; it < 4; ++it) {
    int fid = tid + it * 256;
    int i = fid >> 4, j4 = fid & 15;
    f32x4 v = *(const f32x4*)(xn + (c0 + i) * P_ + p0 + j4 * 4);
    short4v s;
#pragma unroll
    for (int r = 0; r < 4; ++r) s[r] = f2bf(v[r]);
    *(short4v*)(xbn + (c0 + i) * P_ + p0 + j4 * 4) = s;
    *(short4v*)(&Ls[i][j4 * 4]) = s;
  }
  __syncthreads();
#pragma unroll
  for (int it = 0; it < 4; ++it) {
    int oid = tid + it * 256;
    int pr = oid >> 4, cg = oid & 15, cb = cg * 4;
    short4v a;
#pragma unroll
    for (int r = 0; r < 4; ++r) a[r] = Ls[cb + r][pr];
    *(short4v*)(xTn + (p0 + pr) * C_ + c0 + cb) = a;
  }
}

// ---- g12: role1: t3T = w3 @ t1 ; role0: t6T/t7T from w6 @ t5(on-the-fly) ----
__global__ __launch_bounds__(256) void g12_kernel(const short* __restrict__ w3p,
                                                  const short* __restrict__ w6p,
                                                  const float* __restrict__ p5,
                                                  const short* __restrict__ xT,
                                                  short* __restrict__ t3T,
                                                  short* __restrict__ t6T,
                                                  short* __restrict__ t7T) {
  int blk = blockIdx.x;
  int role = blk & 1;                 // 1: g1 (t3), 0: g2 (t6/t7)
  int b = blk >> 1;
  int n = b >> 5, pt = b & 31, p0 = pt * 128;
  int tid = threadIdx.x, lane = tid & 63, wv = tid >> 6;
  int wm = (wv & 1) * 64, wp = (wv >> 1) * 64;
  const short* Ap = role ? w3p : w6p;
  const short* xTn = xT + (size_t)n * CP;
  __shared__ __align__(16) short As[4][128][8];
  __shared__ __align__(16) short Bs[4][128][8];
  f32x4 acc[4][4] = {};
  for (int ks = 0; ks < 12; ++ks) {
    int k0 = ks * 32;
    int jr = ks >> 2;
    __syncthreads();
#pragma unroll
    for (int it = 0; it < 2; ++it) {
      int slot = tid + it * 256;
      int q = slot >> 7, m = slot & 127;
      gl_lds16(Ap + m * K3 + k0 + q * 8, &As[q][m][0]);
    }
#pragma unroll
    for (int it = 0; it < 2; ++it) {
      int slot = tid + it * 256;
      int q = slot & 3, pc = slot >> 2;      // 4 lanes -> one 64B line
      int p = p0 + pc;
      int c0k = ((ks & 3) * 32) + q * 8;
      short8 zero = {};
      short8 v;
      if (role) {
        int d = 2 * (jr - 1);
        int wd = (p & 63) + d;
        bool valid = (wd >= 0 && wd < 64);
        int prc = min(max(p + d, 0), P_ - 1);
        v = *(const short8*)(xTn + (size_t)prc * C_ + c0k);
        if (!valid) v = zero;
      } else {
        int pr = p + 192 * (jr - 1);
        bool rv = (pr >= 0 && pr < P_);
        int prc = min(max(pr, 0), P_ - 1);
        int w2 = prc & 63;
        const short* rb = xTn + (size_t)prc * C_ + c0k;
        short8 vm = *(const short8*)rb;
        short8 vl = (w2 >= 2) ? *(const short8*)(rb - 2 * C_) : zero;
        short8 vr = (w2 < 62) ? *(const short8*)(rb + 2 * C_) : zero;
        float p5v = p5[prc];
#pragma unroll
        for (int jj = 0; jj < 8; ++jj)
          v[jj] = f2bf(p5v * fmaxf(fmaxf(bf2f(vl[jj]), bf2f(vm[jj])), bf2f(vr[jj])));
        if (!rv) v = zero;
      }
      *(short8*)(&Bs[q][pc][0]) = v;
    }
    __syncthreads();
    int row = lane & 15, q = lane >> 4;
    short8 a[4], bb[4];
#pragma unroll
    for (int im = 0; im < 4; ++im) a[im] = *(const short8*)(&As[q][wm + im * 16 + row][0]);
#pragma unroll
    for (int ip = 0; ip < 4; ++ip) bb[ip] = *(const short8*)(&Bs[q][wp + ip * 16 + row][0]);
#pragma unroll
    for (int im = 0; im < 4; ++im)
#pragma unroll
      for (int ip = 0; ip < 4; ++ip)
        acc[im][ip] = __builtin_amdgcn_mfma_f32_16x16x32_bf16(a[im], bb[ip], acc[im][ip], 0, 0, 0);
  }
  int col = lane & 15, rq = lane >> 4;
  if (role) {
    short* t3Tn = t3T + (size_t)n * CP;
#pragma unroll
    for (int im = 0; im < 4; ++im)
#pragma unroll
      for (int ip = 0; ip < 4; ++ip) {
        int m0 = wm + im * 16 + rq * 4;
        int p = p0 + wp + ip * 16 + col;
        short4v s;
#pragma unroll
        for (int r = 0; r < 4; ++r) s[r] = f2bf(acc[im][ip][r]);
        *(short4v*)(t3Tn + (size_t)p * C_ + m0) = s;
      }
  } else {
    short* t6Tn = t6T + (size_t)n * CP;
    short* t7Tn = t7T + (size_t)n * CP;
#pragma unroll
    for (int im = 0; im < 4; ++im)
#pragma unroll
      for (int ip = 0; ip < 4; ++ip) {
        int m0 = wm + im * 16 + rq * 4;
        int p = p0 + wp + ip * 16 + col;
        short4v ax = *(const short4v*)(xTn + (size_t)p * C_ + m0);
        short4v s6, s7;
#pragma unroll
        for (int r = 0; r < 4; ++r) {
          float t6v = acc[im][ip][r];
          float t7v = fmaxf(bf2f(ax[r]), t6v);
          s6[r] = f2bf(t6v);
          s7[r] = f2bf(t7v);
        }
        *(short4v*)(t6Tn + (size_t)p * C_ + m0) = s6;
        *(short4v*)(t7Tn + (size_t)p * C_ + m0) = s7;
      }
  }
}

// ---- g3: t9T[k'=(j,cB)][c] += sum_p t1[k',p] * t7T[p][c]   (split-K=8) ----
__global__ __launch_bounds__(256) void g3_kernel(const short* __restrict__ xb,
                                                 const short* __restrict__ t7T,
                                                 float* __restrict__ t9) {
  int blk = blockIdx.x;                 // 768 = 3 * 32 * 8
  int nb = blk % 3;
  int tmp = blk / 3;
  int n = tmp & 31, sk = tmp >> 5;
  int d = 2 * (nb - 1);                 // uniform shift for all A rows
  int tid = threadIdx.x, lane = tid & 63, wv = tid >> 6;
  int wm = (wv & 1) * 64, wp = (wv >> 1) * 64;
  const short* xbn = xb + (size_t)n * CP;
  const short* t7n = t7T + (size_t)n * CP;
  __shared__ __align__(16) short As[4][128][8];
  __shared__ __align__(16) short Bs[4][128][8];
  f32x4 acc[4][4] = {};
  for (int ks = 0; ks < 16; ++ks) {
    int pp0 = sk * 512 + ks * 32;
    __syncthreads();
    // A rows: t1[nb*128+kc][p] = xb[kc][p+d]
#pragma unroll
    for (int it = 0; it < 2; ++it) {
      int slot = tid + it * 256;
      int q = slot >> 7, kc = slot & 127;
      int pb = pp0 + q * 8;
      const int* src = (const int*)(xbn + kc * P_ + pb + d);   // 4B-aligned
      union { int i[4]; short8 s; } u;
#pragma unroll
      for (int t = 0; t < 4; ++t) u.i[t] = src[t];
      short8 v = u.s;
      int w0 = pb & 63;
      if (nb == 0) { if (w0 == 0) { v[0] = 0; v[1] = 0; } }
      else if (nb == 2) { if (w0 == 56) { v[6] = 0; v[7] = 0; } }
      *(short8*)(&As[q][kc][0]) = v;
    }
    // B: t7T[p][c] row-major; lanes span consecutive c
#pragma unroll
    for (int it = 0; it < 2; ++it) {
      int slot = tid + it * 256;
      int q = slot >> 7, cc = slot & 127;
      const short* bp = t7n + (size_t)(pp0 + q * 8) * C_ + cc;
      short8 v;
#pragma unroll
      for (int j = 0; j < 8; ++j) v[j] = bp[j * C_];
      *(short8*)(&Bs[q][cc][0]) = v;
    }
    __syncthreads();
    int row = lane & 15, q = lane >> 4;
    short8 a[4], bb[4];
#pragma unroll
    for (int im = 0; im < 4; ++im) a[im] = *(const short8*)(&As[q][wm + im * 16 + row][0]);
#pragma unroll
    for (int ip = 0; ip < 4; ++ip) bb[ip] = *(const short8*)(&Bs[q][wp + ip * 16 + row][0]);
#pragma unroll
    for (int im = 0; im < 4; ++im)
#pragma unroll
      for (int ip = 0; ip < 4; ++ip)
        acc[im][ip] = __builtin_amdgcn_mfma_f32_16x16x32_bf16(a[im], bb[ip], acc[im][ip], 0, 0, 0);
  }
  int col = lane & 15, rq = lane >> 4;
  float* t9n = t9 + (size_t)n * (K3 * C_);
#pragma unroll
  for (int im = 0; im < 4; ++im)
#pragma unroll
    for (int ip = 0; ip < 4; ++ip)
#pragma unroll
      for (int r = 0; r < 4; ++r) {
        int kp = nb * 128 + wm + im * 16 + rq * 4 + r;
        int c = wp + ip * 16 + col;
        atomicAdd(&t9n[(size_t)kp * C_ + c], acc[im][ip][r]);   // lane-contiguous
      }
}

// ---- g4: out[c][p] = sum_k' (p8[c]*scale*t9T[k'][c]) * t12[k'][p] ----
__global__ __launch_bounds__(256) void g4_kernel(const float* __restrict__ t9,
                                                 const float* __restrict__ p8,
                                                 const float* __restrict__ p12,
                                                 const short* __restrict__ t3T,
                                                 const short* __restrict__ t6T,
                                                 const short* __restrict__ t7T,
                                                 const short* __restrict__ xT,
                                                 float* __restrict__ out) {
  int b = blockIdx.x;                    // 1024
  int n = b >> 5, pt = b & 31, p0 = pt * 128;
  int tid = threadIdx.x, lane = tid & 63, wv = tid >> 6;
  int wm = (wv & 1) * 64, wp = (wv >> 1) * 64;
  const float* t9n = t9 + (size_t)n * (K3 * C_);
  const short* t3n = t3T + (size_t)n * CP;
  const short* t6n = t6T + (size_t)n * CP;
  const short* t7n = t7T + (size_t)n * CP;
  const short* xTn = xT + (size_t)n * CP;
  const float INV = 1.0f / (64.0f * 19.5959179423f);    // 1/(64*sqrt(384))
  __shared__ __align__(16) short As[4][128][8];
  __shared__ __align__(16) short Bs[4][128][8];
  f32x4 acc[4][4] = {};
  for (int ks = 0; ks < 12; ++ks) {
    int k0 = ks * 32;
    int j = ks >> 2, d = 2 * (j - 1);
    __syncthreads();
    // A[m=c][k'] from t9T[k'][c]: lanes span consecutive c -> coalesced
#pragma unroll
    for (int it = 0; it < 2; ++it) {
      int slot = tid + it * 256;
      int q = slot >> 7, m = slot & 127;
      float sc = p8[m] * INV;
      short8 v;
#pragma unroll
      for (int jj = 0; jj < 8; ++jj)
        v[jj] = f2bf(t9n[(size_t)(k0 + q * 8 + jj) * C_ + m] * sc);
      *(short8*)(&As[q][m][0]) = v;
    }
#pragma unroll
    for (int it = 0; it < 2; ++it) {
      int slot = tid + it * 256;
      int q = slot & 3, pc = slot >> 2;    // 4 lanes -> one 64B line
      int p = p0 + pc;
      int c0k = ((ks & 3) * 32) + q * 8;
      float s12 = p12[j * 64 + (p >> 6)];
      size_t base = (size_t)p * C_ + c0k;
      short8 a6 = *(const short8*)(t6n + base);
      short8 a7 = *(const short8*)(t7n + base);
      short8 a3 = *(const short8*)(t3n + base);
      int wd = (p & 63) + d;
      bool valid = (wd >= 0 && wd < 64);
      int pr = min(max(p + d, 0), P_ - 1);
      short8 ax = *(const short8*)(xTn + (size_t)pr * C_ + c0k);
      short8 zero = {};
      if (!valid) ax = zero;
      short8 v;
#pragma unroll
      for (int jj = 0; jj < 8; ++jj) {
        float t11 = fmaxf(bf2f(a6[jj]), bf2f(a7[jj]) + fmaxf(bf2f(a3[jj]), bf2f(ax[jj])));
        v[jj] = f2bf(s12 * t11);
      }
      *(short8*)(&Bs[q][pc][0]) = v;
    }
    __syncthreads();
    int row = lane & 15, q = lane >> 4;
    short8 a[4], bb[4];
#pragma unroll
    for (int im = 0; im < 4; ++im) a[im] = *(const short8*)(&As[q][wm + im * 16 + row][0]);
#pragma unroll
    for (int ip = 0; ip < 4; ++ip) bb[ip] = *(const short8*)(&Bs[q][wp + ip * 16 + row][0]);
#pragma unroll
    for (int im = 0; im < 4; ++im)
#pragma unroll
      for (int ip = 0; ip < 4; ++ip)
        acc[im][ip] = __builtin_amdgcn_mfma_f32_16x16x32_bf16(a[im], bb[ip], acc[im][ip], 0, 0, 0);
  }
  int col = lane & 15, rq = lane >> 4;
#pragma unroll
  for (int im = 0; im < 4; ++im)
#pragma unroll
    for (int ip = 0; ip < 4; ++ip)
#pragma unroll
      for (int r = 0; r < 4; ++r) {
        int m = wm + im * 16 + rq * 4 + r;
        int p = p0 + wp + ip * 16 + col;
        out[(size_t)n * CP + m * P_ + p] = acc[im][ip][r];
      }
}

extern "C" void kernel_launch(void* const* d_in, const int* in_sizes, int n_in,
                              void* d_out, int out_size, void* d_ws, size_t ws_size,
                              hipStream_t stream) {
  const float* x   = (const float*)d_in[0];
  const float* w3  = (const float*)d_in[1];
  const float* p5  = (const float*)d_in[2];
  const float* w6  = (const float*)d_in[3];
  const float* p8  = (const float*)d_in[4];
  const float* p12 = (const float*)d_in[5];
  float* out = (float*)d_out;

  char* ws = (char*)d_ws;
  const size_t RB = (size_t)NB_ * CP * 2;        // 32 MiB per bf16 tensor
  size_t off = 256;                              // guard for small negative-shift reads
  short* xb  = (short*)(ws + off); off += RB;
  short* xT  = (short*)(ws + off); off += RB;
  short* t3T = (short*)(ws + off); off += RB;
  short* t6T = (short*)(ws + off); off += RB;
  short* t7T = (short*)(ws + off); off += RB;
  float* t9  = (float*)(ws + off); off += (size_t)NB_ * K3 * C_ * 4;   // t9T [n][384][128]
  short* w3p = (short*)(ws + off); off += 49152 * 2;
  short* w6p = (short*)(ws + off); off += 49152 * 2;

  prep_kernel<<<192, 256, 0, stream>>>(w3, w6, w3p, w6p);
  xk_kernel<<<4096, 256, 0, stream>>>(x, xb, xT);
  g12_kernel<<<2048, 256, 0, stream>>>(w3p, w6p, p5, xT, t3T, t6T, t7T);
  hipMemsetAsync(t9, 0, (size_t)NB_ * K3 * C_ * sizeof(float), stream);
  g3_kernel<<<768, 256, 0, stream>>>(xb, t7T, t9);
  g4_kernel<<<1024, 256, 0, stream>>>(t9, p8, p12, t3T, t6T, t7T, xT, out);
}